// Round 2
// baseline (18366.736 us; speedup 1.0000x reference)
//
#include <hip/hip_runtime.h>
#include <hip/hip_bf16.h>
#include <math.h>

// Problem constants (match reference)
#define Bq   8
#define NPix 10000      // 100*100
#define HH   100
#define WW   100
#define Dm   256
#define NH   8
#define HD   32
#define PTS  4
#define FFd  1024
#define Mrows (Bq * NPix)   // 80000

// ---------------------------------------------------------------------------
// Positional encoding + add:  x = src + pe[n]
// ---------------------------------------------------------------------------
__global__ __launch_bounds__(256) void pos_add_kernel(
    const float* __restrict__ src, float* __restrict__ x)
{
    int idx = blockIdx.x * 256 + threadIdx.x;          // 0 .. Mrows*Dm-1
    int c = idx & (Dm - 1);
    int n = (idx >> 8) % NPix;
    int cc = c;
    float coord;
    if (c < 128) { coord = (float)(n / WW); }
    else         { coord = (float)(n % WW); cc = c - 128; }
    int j = cc >> 1;
    float f = __expf(-logf(10000.0f) * (2.0f * (float)j) / 128.0f);
    float arg = coord * f;
    float pe = (cc & 1) ? cosf(arg) : sinf(arg);
    x[idx] = src[idx] + pe;
}

// ---------------------------------------------------------------------------
// Tiled fp32 GEMM: C[M,Nc] = A[M,K] @ W[K,Nc](ldw) + bias
// Optional exact GELU epilogue; optional ACCUM (C += A@W, no bias).
// 256 threads; each thread computes TM x TN. Row-guarded for arbitrary M.
// ---------------------------------------------------------------------------
template<int BM, int BN, int TM, int TN, bool GELU, bool ACCUM>
__global__ __launch_bounds__(256) void gemm_bias_kernel(
    const float* __restrict__ A, const float* __restrict__ W,
    const float* __restrict__ bias, float* __restrict__ C,
    int M, int K, int Nc, int ldw)
{
    constexpr int BK = 16;
    __shared__ float As[BK][BM + 4];
    __shared__ float Bs[BK][BN + 4];
    constexpr int TX = BN / TN;
    constexpr int TY = BM / TM;
    static_assert(TX * TY == 256, "bad tiling");

    const int bm = blockIdx.y * BM;
    const int bn = blockIdx.x * BN;
    const int tid = threadIdx.x;
    const int tx = tid % TX, ty = tid / TX;

    float acc[TM][TN];
    #pragma unroll
    for (int i = 0; i < TM; ++i)
        #pragma unroll
        for (int j = 0; j < TN; ++j) acc[i][j] = 0.0f;

    for (int k0 = 0; k0 < K; k0 += BK) {
        #pragma unroll
        for (int i = tid; i < BM * BK; i += 256) {
            int r = i / BK, c = i % BK;
            int row = bm + r; if (row > M - 1) row = M - 1;   // clamp (store guarded)
            As[c][r] = A[(size_t)row * K + (k0 + c)];
        }
        #pragma unroll
        for (int i = tid; i < BK * BN; i += 256) {
            int kk = i / BN, n = i % BN;
            int col = bn + n;
            Bs[kk][n] = (col < Nc) ? W[(size_t)(k0 + kk) * ldw + col] : 0.0f;
        }
        __syncthreads();
        #pragma unroll
        for (int kk = 0; kk < BK; ++kk) {
            float a[TM], b[TN];
            #pragma unroll
            for (int i = 0; i < TM; ++i) a[i] = As[kk][ty * TM + i];
            #pragma unroll
            for (int j = 0; j < TN; ++j) b[j] = Bs[kk][tx * TN + j];
            #pragma unroll
            for (int i = 0; i < TM; ++i)
                #pragma unroll
                for (int j = 0; j < TN; ++j)
                    acc[i][j] = fmaf(a[i], b[j], acc[i][j]);
        }
        __syncthreads();
    }

    #pragma unroll
    for (int i = 0; i < TM; ++i) {
        int row = bm + ty * TM + i;
        if (row >= M) continue;
        #pragma unroll
        for (int j = 0; j < TN; ++j) {
            int col = bn + tx * TN + j;
            if (col < Nc) {
                size_t ci = (size_t)row * Nc + col;
                float val;
                if (ACCUM) {
                    val = C[ci] + acc[i][j];
                } else {
                    val = acc[i][j] + bias[col];
                    if (GELU)
                        val = 0.5f * val * (1.0f + erff(val * 0.70710678118654752f));
                }
                C[ci] = val;
            }
        }
    }
}

// ---------------------------------------------------------------------------
// Deformable attention sampling over a chunk of whole images.
// v    : [CM, 256]  channel = h*32 + d       (CM = k * NPix)
// off  : [CM, 64]   channel = h*8 + p*2 + {0:dx, 1:dy}
// alog : [CM, 32]   channel = h*4 + p
// out  : [CM, 256]
// 32 lanes handle one (row, h); lane = d. px = col + dx, py = row + dy.
// ---------------------------------------------------------------------------
__global__ __launch_bounds__(256) void deform_attn_kernel(
    const float* __restrict__ v, const float* __restrict__ off,
    const float* __restrict__ alog, float* __restrict__ out)
{
    int g    = blockIdx.x * 8 + (threadIdx.x >> 5);   // group id over (bn, h)
    int lane = threadIdx.x & 31;
    int bn   = g >> 3;            // local row within chunk
    int h    = g & 7;
    int n    = bn % NPix;
    int row  = n / WW, col = n % WW;
    int base_v = (bn / NPix) * NPix;   // image base within chunk

    const float* offp = off  + (size_t)bn * 64 + h * 8;
    const float* ap   = alog + (size_t)bn * 32 + h * 4;

    float l0 = ap[0], l1 = ap[1], l2 = ap[2], l3 = ap[3];
    float mx = fmaxf(fmaxf(l0, l1), fmaxf(l2, l3));
    float e0 = __expf(l0 - mx), e1 = __expf(l1 - mx);
    float e2 = __expf(l2 - mx), e3 = __expf(l3 - mx);
    float inv = 1.0f / (e0 + e1 + e2 + e3);
    float aw[4] = {e0 * inv, e1 * inv, e2 * inv, e3 * inv};

    float acc = 0.0f;
    #pragma unroll
    for (int p = 0; p < 4; ++p) {
        float dx = offp[p * 2 + 0];
        float dy = offp[p * 2 + 1];
        float px = (float)col + dx;
        float py = (float)row + dy;
        float x0f = floorf(px), y0f = floorf(py);
        float wx = px - x0f,  wy = py - y0f;
        int x0i = min(max((int)x0f, 0), WW - 1);
        int y0i = min(max((int)y0f, 0), HH - 1);
        int x1i = min(x0i + 1, WW - 1);
        int y1i = min(y0i + 1, HH - 1);
        size_t ch = (size_t)h * HD + lane;
        float v00 = v[(size_t)(base_v + y0i * WW + x0i) * Dm + ch];
        float v01 = v[(size_t)(base_v + y0i * WW + x1i) * Dm + ch];
        float v10 = v[(size_t)(base_v + y1i * WW + x0i) * Dm + ch];
        float v11 = v[(size_t)(base_v + y1i * WW + x1i) * Dm + ch];
        float s = v00 * (1.0f - wx) * (1.0f - wy)
                + v01 * wx * (1.0f - wy)
                + v10 * (1.0f - wx) * wy
                + v11 * wx * wy;
        acc = fmaf(aw[p], s, acc);
    }
    out[(size_t)bn * Dm + (size_t)h * HD + lane] = acc;
}

// ---------------------------------------------------------------------------
// Fused residual + LayerNorm: out = LN(x + a) * g + b. One wave per row.
// ---------------------------------------------------------------------------
__global__ __launch_bounds__(256) void resid_ln_kernel(
    const float* __restrict__ x, const float* __restrict__ a,
    const float* __restrict__ g, const float* __restrict__ b,
    float* __restrict__ out, int rows)
{
    int row  = blockIdx.x * 4 + (threadIdx.x >> 6);
    if (row >= rows) return;
    int lane = threadIdx.x & 63;
    size_t base = (size_t)row * Dm + lane * 4;

    float4 xv = *reinterpret_cast<const float4*>(x + base);
    float4 av = *reinterpret_cast<const float4*>(a + base);
    float v0 = xv.x + av.x, v1 = xv.y + av.y, v2 = xv.z + av.z, v3 = xv.w + av.w;

    float s = v0 + v1 + v2 + v3;
    #pragma unroll
    for (int o = 32; o >= 1; o >>= 1) s += __shfl_xor(s, o);
    float mean = s * (1.0f / 256.0f);

    float d0 = v0 - mean, d1 = v1 - mean, d2 = v2 - mean, d3 = v3 - mean;
    float q = d0 * d0 + d1 * d1 + d2 * d2 + d3 * d3;
    #pragma unroll
    for (int o = 32; o >= 1; o >>= 1) q += __shfl_xor(q, o);
    float rstd = rsqrtf(q * (1.0f / 256.0f) + 1e-5f);

    float4 gv = *reinterpret_cast<const float4*>(g + lane * 4);
    float4 bv = *reinterpret_cast<const float4*>(b + lane * 4);
    float4 ov;
    ov.x = d0 * rstd * gv.x + bv.x;
    ov.y = d1 * rstd * gv.y + bv.y;
    ov.z = d2 * rstd * gv.z + bv.z;
    ov.w = d3 * rstd * gv.w + bv.w;
    *reinterpret_cast<float4*>(out + base) = ov;
}

// ---------------------------------------------------------------------------
extern "C" void kernel_launch(void* const* d_in, const int* in_sizes, int n_in,
                              void* d_out, int out_size, void* d_ws, size_t ws_size,
                              hipStream_t stream)
{
    const float* src  = (const float*)d_in[0];
    const float* Wv   = (const float*)d_in[1];
    const float* bv   = (const float*)d_in[2];
    const float* Woff = (const float*)d_in[3];
    const float* boff = (const float*)d_in[4];
    const float* Wa   = (const float*)d_in[5];
    const float* ba   = (const float*)d_in[6];
    const float* Wo   = (const float*)d_in[7];
    const float* bo   = (const float*)d_in[8];
    const float* W1   = (const float*)d_in[9];
    const float* b1   = (const float*)d_in[10];
    const float* W2   = (const float*)d_in[11];
    const float* b2   = (const float*)d_in[12];
    const float* g1   = (const float*)d_in[13];
    const float* be1  = (const float*)d_in[14];
    const float* g2   = (const float*)d_in[15];
    const float* be2  = (const float*)d_in[16];

    // x lives in d_out (recomputed from src every call -> deterministic).
    float* x = (float*)d_out;

    // Adaptive chunking: k whole images per chunk.
    // Per-row scratch: v(256) + s(256) + o(256) + off(64) + alog(32) floats
    const size_t perRowB = (size_t)(3 * Dm + 64 + 32) * sizeof(float);  // 3456 B
    int k = 8;
    while (k > 1 && (size_t)k * NPix * perRowB > ws_size) k >>= 1;
    if ((size_t)k * NPix * perRowB > ws_size) return;  // ws hopelessly small
    const int CM = k * NPix;      // rows per chunk
    const int nChunks = Bq / k;

    float* v    = (float*)d_ws;                    // [CM, 256]
    float* sbuf = v    + (size_t)CM * Dm;          // [CM, 256]
    float* o    = sbuf + (size_t)CM * Dm;          // [CM, 256]
    float* off  = o    + (size_t)CM * Dm;          // [CM, 64]
    float* alog = off  + (size_t)CM * 64;          // [CM, 32]

    // x = src + pos_encoding
    pos_add_kernel<<<Mrows, 256, 0, stream>>>(src, x);

    const int gy128 = (CM + 127) / 128;
    const int gy64  = (CM + 63) / 64;
    const int gyLN  = (CM + 3) / 4;

    for (int l = 0; l < 6; ++l) {
        const float* Wv_l   = Wv   + (size_t)l * Dm * Dm;
        const float* Woff_l = Woff + (size_t)l * Dm * 64;
        const float* Wa_l   = Wa   + (size_t)l * Dm * 32;
        const float* Wo_l   = Wo   + (size_t)l * Dm * Dm;
        const float* W1_l   = W1   + (size_t)l * Dm * FFd;
        const float* W2_l   = W2   + (size_t)l * FFd * Dm;

        for (int c = 0; c < nChunks; ++c) {
            float* xc = x + (size_t)c * CM * Dm;

            // v = xc @ Wv + bv
            gemm_bias_kernel<128,128,8,8,false,false><<<dim3(Dm/128, gy128), 256, 0, stream>>>(
                xc, Wv_l, bv + l*Dm, v, CM, Dm, Dm, Dm);
            // off = xc @ Woff + boff
            gemm_bias_kernel<64,64,4,4,false,false><<<dim3(1, gy64), 256, 0, stream>>>(
                xc, Woff_l, boff + l*64, off, CM, Dm, 64, 64);
            // alog = xc @ Wa + ba
            gemm_bias_kernel<64,64,4,4,false,false><<<dim3(1, gy64), 256, 0, stream>>>(
                xc, Wa_l, ba + l*32, alog, CM, Dm, 32, 32);
            // sbuf = deformable sampling
            deform_attn_kernel<<<CM, 256, 0, stream>>>(v, off, alog, sbuf);
            // o = sbuf @ Wo + bo
            gemm_bias_kernel<128,128,8,8,false,false><<<dim3(Dm/128, gy128), 256, 0, stream>>>(
                sbuf, Wo_l, bo + l*Dm, o, CM, Dm, Dm, Dm);
            // xc = LN(xc + o)
            resid_ln_kernel<<<gyLN, 256, 0, stream>>>(xc, o, g1 + l*Dm, be1 + l*Dm, xc, CM);

            // FFN in 4 column strips of 256 (h strip in v, accumulate into sbuf)
            for (int st = 0; st < 4; ++st) {
                // v = gelu(xc @ W1[:, st*256 : st*256+256] + b1[st*256:...])
                gemm_bias_kernel<128,128,8,8,true,false><<<dim3(2, gy128), 256, 0, stream>>>(
                    xc, W1_l + st * 256, b1 + l*FFd + st * 256, v, CM, Dm, 256, FFd);
                // sbuf (st==0: = v @ W2strip + b2 ; else: += v @ W2strip)
                if (st == 0)
                    gemm_bias_kernel<128,128,8,8,false,false><<<dim3(Dm/128, gy128), 256, 0, stream>>>(
                        v, W2_l + (size_t)st * 256 * Dm, b2 + l*Dm, sbuf, CM, 256, Dm, Dm);
                else
                    gemm_bias_kernel<128,128,8,8,false,true><<<dim3(Dm/128, gy128), 256, 0, stream>>>(
                        v, W2_l + (size_t)st * 256 * Dm, b2 + l*Dm, sbuf, CM, 256, Dm, Dm);
            }
            // xc = LN(xc + sbuf)
            resid_ln_kernel<<<gyLN, 256, 0, stream>>>(xc, sbuf, g2 + l*Dm, be2 + l*Dm, xc, CM);
        }
    }
}

// Round 3
// 3281.401 us; speedup vs baseline: 5.5972x; 5.5972x over previous
//
#include <hip/hip_runtime.h>
#include <hip/hip_bf16.h>
#include <math.h>

// Problem constants
#define Bq   8
#define NPix 10000
#define HH   100
#define WW   100
#define Dm   256
#define NH   8
#define HD   32
#define PTS  4
#define FFd  1024
#define Lnum 6
#define Mrows (Bq * NPix)   // 80000

typedef short bf16x8 __attribute__((ext_vector_type(8)));
typedef short short4v __attribute__((ext_vector_type(4)));
typedef float f32x4 __attribute__((ext_vector_type(4)));

__device__ __forceinline__ float bf2f(unsigned short u) {
    return __uint_as_float(((unsigned)u) << 16);
}
__device__ __forceinline__ unsigned short f2bf(float f) {
    unsigned x = __float_as_uint(f);
    return (unsigned short)((x + 0x7fffu + ((x >> 16) & 1u)) >> 16);  // RNE
}

// ---------------------------------------------------------------------------
// Positional encoding + add: x (fp32) and xb (bf16) = src + pe
// ---------------------------------------------------------------------------
__global__ __launch_bounds__(256) void pos_add_kernel(
    const float* __restrict__ src, float* __restrict__ x, short* __restrict__ xb)
{
    int idx = blockIdx.x * 256 + threadIdx.x;
    int c = idx & (Dm - 1);
    int n = (idx >> 8) % NPix;
    int cc = c;
    float coord;
    if (c < 128) { coord = (float)(n / WW); }
    else         { coord = (float)(n % WW); cc = c - 128; }
    int j = cc >> 1;
    float f = __expf(-logf(10000.0f) * (2.0f * (float)j) / 128.0f);
    float arg = coord * f;
    float pe = (cc & 1) ? cosf(arg) : sinf(arg);
    float val = src[idx] + pe;
    x[idx] = val;
    xb[idx] = (short)f2bf(val);
}

// ---------------------------------------------------------------------------
// Weight repack: W[l][K][N] fp32  ->  Wt[l][nOff + n][K] bf16  (transpose)
// 64x64 tiles via LDS.
// ---------------------------------------------------------------------------
__global__ __launch_bounds__(256) void repack_kernel(
    const float* __restrict__ W, short* __restrict__ Wt,
    int K, int N, int outLstride, int nOff)
{
    __shared__ float t[64][65];
    int l  = blockIdx.z;
    int k0 = blockIdx.y * 64, n0 = blockIdx.x * 64;
    const float* Wl = W + (size_t)l * K * N;
    for (int i = threadIdx.x; i < 64 * 64; i += 256) {
        int kk = i >> 6, nn = i & 63;
        float val = 0.0f;
        if (k0 + kk < K && n0 + nn < N) val = Wl[(size_t)(k0 + kk) * N + (n0 + nn)];
        t[kk][nn] = val;
    }
    __syncthreads();
    for (int i = threadIdx.x; i < 64 * 64; i += 256) {
        int nn = i >> 6, kk = i & 63;
        if (n0 + nn < N && k0 + kk < K)
            Wt[(size_t)l * outLstride + (size_t)(nOff + n0 + nn) * K + (k0 + kk)]
                = (short)f2bf(t[kk][nn]);
    }
}

// combined bias for off(64)|alog(32): bc[l][96]
__global__ void bcomb_kernel(const float* __restrict__ boff,
                             const float* __restrict__ ba,
                             float* __restrict__ bc)
{
    int l = blockIdx.x, c = threadIdx.x;   // grid 6 x 96
    bc[l * 96 + c] = (c < 64) ? boff[l * 64 + c] : ba[l * 32 + (c - 64)];
}

// ---------------------------------------------------------------------------
// bf16 MFMA GEMM (m97 structure): C[M,Nc] = A[M,K](bf16) @ Bt[Nc,K]^T (bf16)
//   + bias; optional exact GELU; output bf16 or fp32.
// 128x128 tile, 4 waves (2x2 of 64x64), BK=64, K % 64 == 0.
// LDS linear [row][64] bf16; T2 XOR-swizzle via pre-swizzled global source
// (16B chunk c stores row chunk c ^ (row&7)); ds_read applies same XOR.
// global_load_lds width 16.
// ---------------------------------------------------------------------------
template<bool GELU, bool BF16OUT>
__global__ __launch_bounds__(256) void gemm_mfma_kernel(
    const short* __restrict__ A, const short* __restrict__ Bt,
    const float* __restrict__ bias, void* __restrict__ Cv,
    int M, int K, int Nc, int ldc)
{
    __shared__ short As[128 * 64];
    __shared__ short Bs[128 * 64];
    const int tid = threadIdx.x;
    const int bm = blockIdx.y * 128, bn = blockIdx.x * 128;
    const int w = tid >> 6, l = tid & 63;
    const int wr = (w >> 1) * 64, wc = (w & 1) * 64;

    f32x4 acc[4][4];
    #pragma unroll
    for (int m = 0; m < 4; ++m)
        #pragma unroll
        for (int n = 0; n < 4; ++n)
            #pragma unroll
            for (int j = 0; j < 4; ++j) acc[m][n][j] = 0.0f;

    const int rl = tid >> 3;      // 0..31 (row within pass)
    const int cl = tid & 7;       // chunk 0..7
    const int lr = l & 15, lq = l >> 4;

    for (int k0 = 0; k0 < K; k0 += 64) {
        // ---- stage A and B tiles (4 passes each, 16B per lane) ----
        #pragma unroll
        for (int p = 0; p < 4; ++p) {
            int row = p * 32 + rl;
            int sc  = cl ^ (row & 7);
            int ga  = bm + row; if (ga > M - 1) ga = M - 1;
            const short* gpA = A + (size_t)ga * K + k0 + sc * 8;
            __builtin_amdgcn_global_load_lds((const void*)gpA,
                (void*)&As[(p * 32 + w * 8) * 64], 16, 0, 0);
            int gb = bn + row; if (gb > Nc - 1) gb = Nc - 1;
            const short* gpB = Bt + (size_t)gb * K + k0 + sc * 8;
            __builtin_amdgcn_global_load_lds((const void*)gpB,
                (void*)&Bs[(p * 32 + w * 8) * 64], 16, 0, 0);
        }
        __syncthreads();   // drains vmcnt before barrier

        // ---- 2 MFMA K-steps of 32 ----
        #pragma unroll
        for (int ks = 0; ks < 2; ++ks) {
            bf16x8 af[4], bfr[4];
            #pragma unroll
            for (int m = 0; m < 4; ++m) {
                int row = wr + m * 16 + lr;
                int ch  = (ks * 4 + lq) ^ (row & 7);
                af[m] = *(const bf16x8*)&As[row * 64 + ch * 8];
            }
            #pragma unroll
            for (int n = 0; n < 4; ++n) {
                int row = wc + n * 16 + lr;
                int ch  = (ks * 4 + lq) ^ (row & 7);
                bfr[n] = *(const bf16x8*)&Bs[row * 64 + ch * 8];
            }
            #pragma unroll
            for (int m = 0; m < 4; ++m)
                #pragma unroll
                for (int n = 0; n < 4; ++n)
                    acc[m][n] = __builtin_amdgcn_mfma_f32_16x16x32_bf16(
                        af[m], bfr[n], acc[m][n], 0, 0, 0);
        }
        __syncthreads();
    }

    // ---- epilogue: bias (+GELU), store ----
    #pragma unroll
    for (int m = 0; m < 4; ++m) {
        int row0 = bm + wr + m * 16 + lq * 4;
        #pragma unroll
        for (int n = 0; n < 4; ++n) {
            int col = bn + wc + n * 16 + lr;
            if (col >= Nc) continue;
            float bi = bias[col];
            #pragma unroll
            for (int j = 0; j < 4; ++j) {
                int r = row0 + j;
                if (r >= M) continue;
                float val = acc[m][n][j] + bi;
                if (GELU)
                    val = 0.5f * val * (1.0f + erff(val * 0.70710678118654752f));
                if (BF16OUT)
                    ((short*)Cv)[(size_t)r * ldc + col] = (short)f2bf(val);
                else
                    ((float*)Cv)[(size_t)r * ldc + col] = val;
            }
        }
    }
}

// ---------------------------------------------------------------------------
// Deformable sampling. v bf16 [CM,256] (ch = h*32+d), comb fp32 [CM,96]
// (0..63: off ch = h*8+p*2+{dx,dy}; 64..95: alog ch = h*4+p), out bf16.
// 16 lanes per (row,h); each lane covers 2 channels via uint loads.
// ---------------------------------------------------------------------------
__global__ __launch_bounds__(256) void deform_attn_kernel(
    const short* __restrict__ v, const float* __restrict__ comb,
    short* __restrict__ outs)
{
    int g  = blockIdx.x * 16 + (threadIdx.x >> 4);   // g = bn*8 + h
    int d2 = threadIdx.x & 15;
    int bn = g >> 3, h = g & 7;
    int n  = bn % NPix;
    int row = n / WW, col = n % WW;
    int base_v = (bn / NPix) * NPix;

    const float* cb = comb + (size_t)bn * 96;
    float l0 = cb[64 + h * 4 + 0], l1 = cb[64 + h * 4 + 1];
    float l2 = cb[64 + h * 4 + 2], l3 = cb[64 + h * 4 + 3];
    float mx = fmaxf(fmaxf(l0, l1), fmaxf(l2, l3));
    float e0 = __expf(l0 - mx), e1 = __expf(l1 - mx);
    float e2 = __expf(l2 - mx), e3 = __expf(l3 - mx);
    float inv = 1.0f / (e0 + e1 + e2 + e3);
    float aw[4] = {e0 * inv, e1 * inv, e2 * inv, e3 * inv};

    float acc0 = 0.0f, acc1 = 0.0f;
    size_t chb = (size_t)h * HD + d2 * 2;
    #pragma unroll
    for (int p = 0; p < 4; ++p) {
        float dx = cb[h * 8 + p * 2 + 0];
        float dy = cb[h * 8 + p * 2 + 1];
        float px = (float)col + dx;
        float py = (float)row + dy;
        float x0f = floorf(px), y0f = floorf(py);
        float wx = px - x0f, wy = py - y0f;
        int x0i = min(max((int)x0f, 0), WW - 1);
        int y0i = min(max((int)y0f, 0), HH - 1);
        int x1i = min(x0i + 1, WW - 1);
        int y1i = min(y0i + 1, HH - 1);
        unsigned u00 = *(const unsigned*)&v[(size_t)(base_v + y0i * WW + x0i) * Dm + chb];
        unsigned u01 = *(const unsigned*)&v[(size_t)(base_v + y0i * WW + x1i) * Dm + chb];
        unsigned u10 = *(const unsigned*)&v[(size_t)(base_v + y1i * WW + x0i) * Dm + chb];
        unsigned u11 = *(const unsigned*)&v[(size_t)(base_v + y1i * WW + x1i) * Dm + chb];
        float w00 = (1.0f - wx) * (1.0f - wy), w01 = wx * (1.0f - wy);
        float w10 = (1.0f - wx) * wy,          w11 = wx * wy;
        float s0 = bf2f((unsigned short)u00) * w00 + bf2f((unsigned short)u01) * w01
                 + bf2f((unsigned short)u10) * w10 + bf2f((unsigned short)u11) * w11;
        float s1 = bf2f((unsigned short)(u00 >> 16)) * w00 + bf2f((unsigned short)(u01 >> 16)) * w01
                 + bf2f((unsigned short)(u10 >> 16)) * w10 + bf2f((unsigned short)(u11 >> 16)) * w11;
        acc0 = fmaf(aw[p], s0, acc0);
        acc1 = fmaf(aw[p], s1, acc1);
    }
    unsigned outw = (unsigned)f2bf(acc0) | ((unsigned)f2bf(acc1) << 16);
    *(unsigned*)&outs[(size_t)bn * Dm + chb] = outw;
}

// ---------------------------------------------------------------------------
// Fused residual + LayerNorm -> fp32 x and bf16 xb. One wave per row.
// ---------------------------------------------------------------------------
__global__ __launch_bounds__(256) void resid_ln_kernel(
    const float* __restrict__ x, const float* __restrict__ a,
    const float* __restrict__ g, const float* __restrict__ b,
    float* __restrict__ out, short* __restrict__ outb, int rows)
{
    int row  = blockIdx.x * 4 + (threadIdx.x >> 6);
    if (row >= rows) return;
    int lane = threadIdx.x & 63;
    size_t base = (size_t)row * Dm + lane * 4;

    float4 xv = *reinterpret_cast<const float4*>(x + base);
    float4 av = *reinterpret_cast<const float4*>(a + base);
    float v0 = xv.x + av.x, v1 = xv.y + av.y, v2 = xv.z + av.z, v3 = xv.w + av.w;

    float s = v0 + v1 + v2 + v3;
    #pragma unroll
    for (int o = 32; o >= 1; o >>= 1) s += __shfl_xor(s, o);
    float mean = s * (1.0f / 256.0f);

    float d0 = v0 - mean, d1 = v1 - mean, d2 = v2 - mean, d3 = v3 - mean;
    float q = d0 * d0 + d1 * d1 + d2 * d2 + d3 * d3;
    #pragma unroll
    for (int o = 32; o >= 1; o >>= 1) q += __shfl_xor(q, o);
    float rstd = rsqrtf(q * (1.0f / 256.0f) + 1e-5f);

    float4 gv = *reinterpret_cast<const float4*>(g + lane * 4);
    float4 bv = *reinterpret_cast<const float4*>(b + lane * 4);
    float4 ov;
    ov.x = d0 * rstd * gv.x + bv.x;
    ov.y = d1 * rstd * gv.y + bv.y;
    ov.z = d2 * rstd * gv.z + bv.z;
    ov.w = d3 * rstd * gv.w + bv.w;
    *reinterpret_cast<float4*>(out + base) = ov;
    short4v sb;
    sb.x = (short)f2bf(ov.x); sb.y = (short)f2bf(ov.y);
    sb.z = (short)f2bf(ov.z); sb.w = (short)f2bf(ov.w);
    *reinterpret_cast<short4v*>(outb + base) = sb;
}

// ---------------------------------------------------------------------------
extern "C" void kernel_launch(void* const* d_in, const int* in_sizes, int n_in,
                              void* d_out, int out_size, void* d_ws, size_t ws_size,
                              hipStream_t stream)
{
    const float* src  = (const float*)d_in[0];
    const float* Wv   = (const float*)d_in[1];
    const float* bv   = (const float*)d_in[2];
    const float* Woff = (const float*)d_in[3];
    const float* boff = (const float*)d_in[4];
    const float* Wa   = (const float*)d_in[5];
    const float* ba   = (const float*)d_in[6];
    const float* Wo   = (const float*)d_in[7];
    const float* bo   = (const float*)d_in[8];
    const float* W1   = (const float*)d_in[9];
    const float* b1   = (const float*)d_in[10];
    const float* W2   = (const float*)d_in[11];
    const float* b2   = (const float*)d_in[12];
    const float* g1   = (const float*)d_in[13];
    const float* be1  = (const float*)d_in[14];
    const float* g2   = (const float*)d_in[15];
    const float* be2  = (const float*)d_in[16];

    float* x = (float*)d_out;   // fp32 master activations

    // ---- workspace layout ----
    char* cur = (char*)d_ws;
    auto take = [&](size_t bytes) { char* p = cur; cur += (bytes + 255) & ~(size_t)255; return p; };
    short* WvT = (short*)take((size_t)Lnum * Dm * Dm * 2);
    short* WoT = (short*)take((size_t)Lnum * Dm * Dm * 2);
    short* W1T = (short*)take((size_t)Lnum * Dm * FFd * 2);   // [l][1024][256]
    short* W2T = (short*)take((size_t)Lnum * FFd * Dm * 2);   // [l][256][1024]
    short* WcT = (short*)take((size_t)Lnum * 96 * Dm * 2);    // [l][96][256]
    float* bc  = (float*)take((size_t)Lnum * 96 * 4);
    short* xb  = (short*)take((size_t)Mrows * Dm * 2);        // bf16 shadow of x
    size_t fixedB = (size_t)(cur - (char*)d_ws);

    const size_t perRowB = 512 + 512 + 384 + 1024 + 2048;     // v,s,comb,o,h
    int k = 8;
    while (k > 1 && fixedB + (size_t)k * NPix * perRowB > ws_size) k >>= 1;
    if (fixedB + (size_t)k * NPix * perRowB > ws_size) return;
    const int CM = k * NPix;
    const int nChunks = Bq / k;

    short* v    = (short*)take((size_t)CM * Dm * 2);
    short* sbuf = (short*)take((size_t)CM * Dm * 2);
    float* comb = (float*)take((size_t)CM * 96 * 4);
    float* o    = (float*)take((size_t)CM * Dm * 4);
    short* h    = (short*)take((size_t)CM * FFd * 2);

    // ---- weight repack (bf16, transposed) ----
    repack_kernel<<<dim3(4, 4, Lnum),  256, 0, stream>>>(Wv,   WvT, Dm,  Dm,  Dm * Dm,   0);
    repack_kernel<<<dim3(4, 4, Lnum),  256, 0, stream>>>(Wo,   WoT, Dm,  Dm,  Dm * Dm,   0);
    repack_kernel<<<dim3(16, 4, Lnum), 256, 0, stream>>>(W1,   W1T, Dm,  FFd, Dm * FFd,  0);
    repack_kernel<<<dim3(4, 16, Lnum), 256, 0, stream>>>(W2,   W2T, FFd, Dm,  FFd * Dm,  0);
    repack_kernel<<<dim3(1, 4, Lnum),  256, 0, stream>>>(Woff, WcT, Dm,  64,  96 * Dm,   0);
    repack_kernel<<<dim3(1, 4, Lnum),  256, 0, stream>>>(Wa,   WcT, Dm,  32,  96 * Dm,  64);
    bcomb_kernel<<<Lnum, 96, 0, stream>>>(boff, ba, bc);

    // x = src + pos encoding (fp32 + bf16)
    pos_add_kernel<<<Mrows, 256, 0, stream>>>(src, x, xb);

    const int gy  = (CM + 127) / 128;
    const int gLN = (CM + 3) / 4;

    for (int l = 0; l < Lnum; ++l) {
        const short* WvT_l = WvT + (size_t)l * Dm * Dm;
        const short* WoT_l = WoT + (size_t)l * Dm * Dm;
        const short* W1T_l = W1T + (size_t)l * Dm * FFd;
        const short* W2T_l = W2T + (size_t)l * FFd * Dm;
        const short* WcT_l = WcT + (size_t)l * 96 * Dm;

        for (int c = 0; c < nChunks; ++c) {
            size_t rowOff = (size_t)c * CM;
            float* xc  = x  + rowOff * Dm;
            short* xbc = xb + rowOff * Dm;

            // v = xb @ WvT (bf16 out)
            gemm_mfma_kernel<false, true><<<dim3(2, gy), 256, 0, stream>>>(
                xbc, WvT_l, bv + l * Dm, v, CM, Dm, Dm, Dm);
            // comb = xb @ WcT (fp32 out, 96 cols)
            gemm_mfma_kernel<false, false><<<dim3(1, gy), 256, 0, stream>>>(
                xbc, WcT_l, bc + l * 96, comb, CM, Dm, 96, 96);
            // sbuf = deformable sampling (bf16)
            deform_attn_kernel<<<CM / 2, 256, 0, stream>>>(v, comb, sbuf);
            // o = sbuf @ WoT (fp32 out)
            gemm_mfma_kernel<false, false><<<dim3(2, gy), 256, 0, stream>>>(
                sbuf, WoT_l, bo + l * Dm, o, CM, Dm, Dm, Dm);
            // x = LN(x + o); xb = bf16(x)
            resid_ln_kernel<<<gLN, 256, 0, stream>>>(
                xc, o, g1 + l * Dm, be1 + l * Dm, xc, xbc, CM);
            // h = gelu(xb @ W1T) (bf16 out)
            gemm_mfma_kernel<true, true><<<dim3(8, gy), 256, 0, stream>>>(
                xbc, W1T_l, b1 + l * FFd, h, CM, Dm, FFd, FFd);
            // o = h @ W2T (fp32 out)
            gemm_mfma_kernel<false, false><<<dim3(2, gy), 256, 0, stream>>>(
                h, W2T_l, b2 + l * Dm, o, CM, FFd, Dm, Dm);
            // x = LN(x + o); xb = bf16(x)
            resid_ln_kernel<<<gLN, 256, 0, stream>>>(
                xc, o, g2 + l * Dm, be2 + l * Dm, xc, xbc, CM);
        }
    }
}

// Round 4
// 2705.901 us; speedup vs baseline: 6.7877x; 1.2127x over previous
//
#include <hip/hip_runtime.h>
#include <hip/hip_bf16.h>
#include <math.h>

// Problem constants
#define Bq   8
#define NPix 10000
#define HH   100
#define WW   100
#define Dm   256
#define NH   8
#define HD   32
#define PTS  4
#define FFd  1024
#define Lnum 6
#define Mrows (Bq * NPix)   // 80000

typedef short bf16x8 __attribute__((ext_vector_type(8)));
typedef short short4v __attribute__((ext_vector_type(4)));
typedef float f32x4 __attribute__((ext_vector_type(4)));

__device__ __forceinline__ float bf2f(unsigned short u) {
    return __uint_as_float(((unsigned)u) << 16);
}
__device__ __forceinline__ unsigned short f2bf(float f) {
    unsigned x = __float_as_uint(f);
    return (unsigned short)((x + 0x7fffu + ((x >> 16) & 1u)) >> 16);  // RNE
}

// ---------------------------------------------------------------------------
// Positional encoding + add: x (fp32) and xb (bf16) = src + pe
// ---------------------------------------------------------------------------
__global__ __launch_bounds__(256) void pos_add_kernel(
    const float* __restrict__ src, float* __restrict__ x, short* __restrict__ xb)
{
    int idx = blockIdx.x * 256 + threadIdx.x;
    int c = idx & (Dm - 1);
    int n = (idx >> 8) % NPix;
    int cc = c;
    float coord;
    if (c < 128) { coord = (float)(n / WW); }
    else         { coord = (float)(n % WW); cc = c - 128; }
    int j = cc >> 1;
    float f = __expf(-logf(10000.0f) * (2.0f * (float)j) / 128.0f);
    float arg = coord * f;
    float pe = (cc & 1) ? cosf(arg) : sinf(arg);
    float val = src[idx] + pe;
    x[idx] = val;
    xb[idx] = (short)f2bf(val);
}

// ---------------------------------------------------------------------------
// Weight repack: W[l][K][N] fp32 -> Wt[l][nOff + n][K] bf16 (transpose)
// ---------------------------------------------------------------------------
__global__ __launch_bounds__(256) void repack_kernel(
    const float* __restrict__ W, short* __restrict__ Wt,
    int K, int N, int outLstride, int nOff)
{
    __shared__ float t[64][65];
    int l  = blockIdx.z;
    int k0 = blockIdx.y * 64, n0 = blockIdx.x * 64;
    const float* Wl = W + (size_t)l * K * N;
    for (int i = threadIdx.x; i < 64 * 64; i += 256) {
        int kk = i >> 6, nn = i & 63;
        float val = 0.0f;
        if (k0 + kk < K && n0 + nn < N) val = Wl[(size_t)(k0 + kk) * N + (n0 + nn)];
        t[kk][nn] = val;
    }
    __syncthreads();
    for (int i = threadIdx.x; i < 64 * 64; i += 256) {
        int nn = i >> 6, kk = i & 63;
        if (n0 + nn < N && k0 + kk < K)
            Wt[(size_t)l * outLstride + (size_t)(nOff + n0 + nn) * K + (k0 + kk)]
                = (short)f2bf(t[kk][nn]);
    }
}

// combined bias: bcat[l][352] = bv(256) | boff(64) | ba(32)
__global__ void bcat_kernel(const float* __restrict__ bv,
                            const float* __restrict__ boff,
                            const float* __restrict__ ba,
                            float* __restrict__ bcat)
{
    int l = blockIdx.x, c = threadIdx.x;   // grid Lnum x 352
    float v;
    if (c < 256)      v = bv[l * 256 + c];
    else if (c < 320) v = boff[l * 64 + (c - 256)];
    else              v = ba[l * 32 + (c - 320)];
    bcat[l * 352 + c] = v;
}

// ---------------------------------------------------------------------------
// bf16 MFMA GEMM, m97 structure, 128x128 tile, 4 waves, BK=64.
// MODE 1: C = bf16, ldc given, optional GELU (W1 path).
// MODE 2: split output: cols <256 -> v (bf16, ldc 256); cols 256..351 ->
//         comb (fp32, ldc 96).  (WvWc path)
// XCD-aware bijective block swizzle (m204) on the flat block id.
// ---------------------------------------------------------------------------
template<bool GELU, int MODE>
__global__ __launch_bounds__(256) void gemm_mfma_kernel(
    const short* __restrict__ A, const short* __restrict__ Bt,
    const float* __restrict__ bias, void* __restrict__ Cv,
    float* __restrict__ C2,
    int M, int K, int Nc, int ldc)
{
    __shared__ short As[128 * 64];
    __shared__ short Bs[128 * 64];
    const int tid = threadIdx.x;

    // XCD swizzle (bijective for any nwg)
    int nwg  = gridDim.x * gridDim.y;
    int orig = blockIdx.y * gridDim.x + blockIdx.x;
    int xcd  = orig & 7, pos = orig >> 3;
    int q = nwg >> 3, r = nwg & 7;
    int flat = (xcd < r ? xcd * (q + 1) : r * (q + 1) + (xcd - r) * q) + pos;
    const int bm = (flat / gridDim.x) * 128;
    const int bn = (flat % gridDim.x) * 128;

    const int w = tid >> 6, l = tid & 63;
    const int wr = (w >> 1) * 64, wc = (w & 1) * 64;

    f32x4 acc[4][4];
    #pragma unroll
    for (int m = 0; m < 4; ++m)
        #pragma unroll
        for (int n = 0; n < 4; ++n)
            #pragma unroll
            for (int j = 0; j < 4; ++j) acc[m][n][j] = 0.0f;

    const int rl = tid >> 3;      // 0..31
    const int cl = tid & 7;       // chunk 0..7
    const int lr = l & 15, lq = l >> 4;

    for (int k0 = 0; k0 < K; k0 += 64) {
        #pragma unroll
        for (int p = 0; p < 4; ++p) {
            int row = p * 32 + rl;
            int sc  = cl ^ (row & 7);
            int ga  = bm + row; if (ga > M - 1) ga = M - 1;
            __builtin_amdgcn_global_load_lds((const void*)(A + (size_t)ga * K + k0 + sc * 8),
                (void*)&As[(p * 32 + w * 8) * 64], 16, 0, 0);
            int gb = bn + row; if (gb > Nc - 1) gb = Nc - 1;
            __builtin_amdgcn_global_load_lds((const void*)(Bt + (size_t)gb * K + k0 + sc * 8),
                (void*)&Bs[(p * 32 + w * 8) * 64], 16, 0, 0);
        }
        __syncthreads();

        #pragma unroll
        for (int ks = 0; ks < 2; ++ks) {
            bf16x8 af[4], bfr[4];
            #pragma unroll
            for (int m = 0; m < 4; ++m) {
                int row = wr + m * 16 + lr;
                int ch  = (ks * 4 + lq) ^ (row & 7);
                af[m] = *(const bf16x8*)&As[row * 64 + ch * 8];
            }
            #pragma unroll
            for (int n = 0; n < 4; ++n) {
                int row = wc + n * 16 + lr;
                int ch  = (ks * 4 + lq) ^ (row & 7);
                bfr[n] = *(const bf16x8*)&Bs[row * 64 + ch * 8];
            }
            #pragma unroll
            for (int m = 0; m < 4; ++m)
                #pragma unroll
                for (int n = 0; n < 4; ++n)
                    acc[m][n] = __builtin_amdgcn_mfma_f32_16x16x32_bf16(
                        af[m], bfr[n], acc[m][n], 0, 0, 0);
        }
        __syncthreads();
    }

    #pragma unroll
    for (int m = 0; m < 4; ++m) {
        int row0 = bm + wr + m * 16 + lq * 4;
        #pragma unroll
        for (int n = 0; n < 4; ++n) {
            int col = bn + wc + n * 16 + lr;
            if (col >= Nc) continue;
            float bi = bias[col];
            #pragma unroll
            for (int j = 0; j < 4; ++j) {
                int rr = row0 + j;
                if (rr >= M) continue;
                float val = acc[m][n][j] + bi;
                if (GELU)
                    val = 0.5f * val * (1.0f + erff(val * 0.70710678118654752f));
                if (MODE == 1) {
                    ((short*)Cv)[(size_t)rr * ldc + col] = (short)f2bf(val);
                } else {  // MODE == 2: split
                    if (col < 256)
                        ((short*)Cv)[(size_t)rr * 256 + col] = (short)f2bf(val);
                    else
                        C2[(size_t)rr * 96 + (col - 256)] = val;
                }
            }
        }
    }
}

// ---------------------------------------------------------------------------
// bf16 MFMA GEMM + fused residual+LayerNorm epilogue.
// C_pre = A[M,K] @ Bt[256,K]^T + bias;  x = LN(x + C_pre)*g + be; xb = bf16(x).
// BM=64, BN=256 (full row in block), 4 waves, each wave owns 16 rows x 256
// cols -> LN row reduce is in-wave shfl_xor over the 16 lr lanes.
// ---------------------------------------------------------------------------
__global__ __launch_bounds__(256) void gemm_ln_kernel(
    const short* __restrict__ A, const short* __restrict__ Bt,
    const float* __restrict__ bias,
    const float* __restrict__ gw, const float* __restrict__ bw,
    float* __restrict__ x, short* __restrict__ xb,
    int M, int K)
{
    __shared__ short As[64 * 64];    // 8 KB
    __shared__ short Bs[256 * 64];   // 32 KB
    const int tid = threadIdx.x;
    const int bm = blockIdx.x * 64;
    const int w = tid >> 6, l = tid & 63;
    const int rl = tid >> 3, cl = tid & 7;
    const int lr = l & 15, lq = l >> 4;

    f32x4 acc[16];
    #pragma unroll
    for (int n = 0; n < 16; ++n)
        #pragma unroll
        for (int j = 0; j < 4; ++j) acc[n][j] = 0.0f;

    for (int k0 = 0; k0 < K; k0 += 64) {
        // A: 64 rows, 2 passes of 32
        #pragma unroll
        for (int p = 0; p < 2; ++p) {
            int row = p * 32 + rl;
            int sc  = cl ^ (row & 7);
            int ga  = bm + row; if (ga > M - 1) ga = M - 1;
            __builtin_amdgcn_global_load_lds((const void*)(A + (size_t)ga * K + k0 + sc * 8),
                (void*)&As[(p * 32 + w * 8) * 64], 16, 0, 0);
        }
        // B: 256 rows, 8 passes of 32 (rows always < 256 valid)
        #pragma unroll
        for (int p = 0; p < 8; ++p) {
            int row = p * 32 + rl;
            int sc  = cl ^ (row & 7);
            __builtin_amdgcn_global_load_lds((const void*)(Bt + (size_t)row * K + k0 + sc * 8),
                (void*)&Bs[(p * 32 + w * 8) * 64], 16, 0, 0);
        }
        __syncthreads();

        #pragma unroll
        for (int ks = 0; ks < 2; ++ks) {
            int arow = w * 16 + lr;
            bf16x8 af = *(const bf16x8*)&As[arow * 64 + (((ks * 4 + lq) ^ (arow & 7))) * 8];
            #pragma unroll
            for (int hb = 0; hb < 2; ++hb) {
                bf16x8 bfr[8];
                #pragma unroll
                for (int i = 0; i < 8; ++i) {
                    int brow = (hb * 8 + i) * 16 + lr;
                    bfr[i] = *(const bf16x8*)&Bs[brow * 64 + (((ks * 4 + lq) ^ (brow & 7))) * 8];
                }
                #pragma unroll
                for (int i = 0; i < 8; ++i)
                    acc[hb * 8 + i] = __builtin_amdgcn_mfma_f32_16x16x32_bf16(
                        af, bfr[i], acc[hb * 8 + i], 0, 0, 0);
            }
        }
        __syncthreads();
    }

    // ---- epilogue: bias + residual + LayerNorm, write x (fp32) + xb (bf16)
    float bi[16];
    #pragma unroll
    for (int n = 0; n < 16; ++n) bi[n] = bias[n * 16 + lr];

    #pragma unroll
    for (int j = 0; j < 4; ++j) {
        int rr = bm + w * 16 + lq * 4 + j;   // uniform across the 16 lr lanes
        if (rr < M) {
            float tmp[16];
            float sum = 0.0f;
            #pragma unroll
            for (int n = 0; n < 16; ++n) {
                int c = n * 16 + lr;
                float val = acc[n][j] + bi[n] + x[(size_t)rr * 256 + c];
                tmp[n] = val;
                sum += val;
            }
            #pragma unroll
            for (int o = 8; o >= 1; o >>= 1) sum += __shfl_xor(sum, o);
            float mean = sum * (1.0f / 256.0f);
            float vs = 0.0f;
            #pragma unroll
            for (int n = 0; n < 16; ++n) {
                float d = tmp[n] - mean;
                vs += d * d;
            }
            #pragma unroll
            for (int o = 8; o >= 1; o >>= 1) vs += __shfl_xor(vs, o);
            float rstd = rsqrtf(vs * (1.0f / 256.0f) + 1e-5f);
            #pragma unroll
            for (int n = 0; n < 16; ++n) {
                int c = n * 16 + lr;
                float ov = (tmp[n] - mean) * rstd * gw[c] + bw[c];
                x[(size_t)rr * 256 + c] = ov;
                xb[(size_t)rr * 256 + c] = (short)f2bf(ov);
            }
        }
    }
}

// ---------------------------------------------------------------------------
// Deformable sampling. v bf16 [CM,256], comb fp32 [CM,96], out bf16 [CM,256].
// 16 lanes per (row,h); each lane covers 2 channels.
// ---------------------------------------------------------------------------
__global__ __launch_bounds__(256) void deform_attn_kernel(
    const short* __restrict__ v, const float* __restrict__ comb,
    short* __restrict__ outs)
{
    int g  = blockIdx.x * 16 + (threadIdx.x >> 4);
    int d2 = threadIdx.x & 15;
    int bn = g >> 3, h = g & 7;
    int n  = bn % NPix;
    int row = n / WW, col = n % WW;
    int base_v = (bn / NPix) * NPix;

    const float* cb = comb + (size_t)bn * 96;
    float l0 = cb[64 + h * 4 + 0], l1 = cb[64 + h * 4 + 1];
    float l2 = cb[64 + h * 4 + 2], l3 = cb[64 + h * 4 + 3];
    float mx = fmaxf(fmaxf(l0, l1), fmaxf(l2, l3));
    float e0 = __expf(l0 - mx), e1 = __expf(l1 - mx);
    float e2 = __expf(l2 - mx), e3 = __expf(l3 - mx);
    float inv = 1.0f / (e0 + e1 + e2 + e3);
    float aw[4] = {e0 * inv, e1 * inv, e2 * inv, e3 * inv};

    float acc0 = 0.0f, acc1 = 0.0f;
    size_t chb = (size_t)h * HD + d2 * 2;
    #pragma unroll
    for (int p = 0; p < 4; ++p) {
        float dx = cb[h * 8 + p * 2 + 0];
        float dy = cb[h * 8 + p * 2 + 1];
        float px = (float)col + dx;
        float py = (float)row + dy;
        float x0f = floorf(px), y0f = floorf(py);
        float wx = px - x0f, wy = py - y0f;
        int x0i = min(max((int)x0f, 0), WW - 1);
        int y0i = min(max((int)y0f, 0), HH - 1);
        int x1i = min(x0i + 1, WW - 1);
        int y1i = min(y0i + 1, HH - 1);
        unsigned u00 = *(const unsigned*)&v[(size_t)(base_v + y0i * WW + x0i) * Dm + chb];
        unsigned u01 = *(const unsigned*)&v[(size_t)(base_v + y0i * WW + x1i) * Dm + chb];
        unsigned u10 = *(const unsigned*)&v[(size_t)(base_v + y1i * WW + x0i) * Dm + chb];
        unsigned u11 = *(const unsigned*)&v[(size_t)(base_v + y1i * WW + x1i) * Dm + chb];
        float w00 = (1.0f - wx) * (1.0f - wy), w01 = wx * (1.0f - wy);
        float w10 = (1.0f - wx) * wy,          w11 = wx * wy;
        float s0 = bf2f((unsigned short)u00) * w00 + bf2f((unsigned short)u01) * w01
                 + bf2f((unsigned short)u10) * w10 + bf2f((unsigned short)u11) * w11;
        float s1 = bf2f((unsigned short)(u00 >> 16)) * w00 + bf2f((unsigned short)(u01 >> 16)) * w01
                 + bf2f((unsigned short)(u10 >> 16)) * w10 + bf2f((unsigned short)(u11 >> 16)) * w11;
        acc0 = fmaf(aw[p], s0, acc0);
        acc1 = fmaf(aw[p], s1, acc1);
    }
    unsigned outw = (unsigned)f2bf(acc0) | ((unsigned)f2bf(acc1) << 16);
    *(unsigned*)&outs[(size_t)bn * Dm + chb] = outw;
}

// ---------------------------------------------------------------------------
extern "C" void kernel_launch(void* const* d_in, const int* in_sizes, int n_in,
                              void* d_out, int out_size, void* d_ws, size_t ws_size,
                              hipStream_t stream)
{
    const float* src  = (const float*)d_in[0];
    const float* Wv   = (const float*)d_in[1];
    const float* bv   = (const float*)d_in[2];
    const float* Woff = (const float*)d_in[3];
    const float* boff = (const float*)d_in[4];
    const float* Wa   = (const float*)d_in[5];
    const float* ba   = (const float*)d_in[6];
    const float* Wo   = (const float*)d_in[7];
    const float* bo   = (const float*)d_in[8];
    const float* W1   = (const float*)d_in[9];
    const float* b1   = (const float*)d_in[10];
    const float* W2   = (const float*)d_in[11];
    const float* b2   = (const float*)d_in[12];
    const float* g1   = (const float*)d_in[13];
    const float* be1  = (const float*)d_in[14];
    const float* g2   = (const float*)d_in[15];
    const float* be2  = (const float*)d_in[16];

    float* x = (float*)d_out;   // fp32 master activations

    // ---- workspace layout ----
    char* cur = (char*)d_ws;
    auto take = [&](size_t bytes) { char* p = cur; cur += (bytes + 255) & ~(size_t)255; return p; };
    short* WcatT = (short*)take((size_t)Lnum * 352 * Dm * 2);  // [l][352][256]
    short* WoT   = (short*)take((size_t)Lnum * Dm * Dm * 2);   // [l][256][256]
    short* W1T   = (short*)take((size_t)Lnum * Dm * FFd * 2);  // [l][1024][256]
    short* W2T   = (short*)take((size_t)Lnum * FFd * Dm * 2);  // [l][256][1024]
    float* bcat  = (float*)take((size_t)Lnum * 352 * 4);
    short* xb    = (short*)take((size_t)Mrows * Dm * 2);       // bf16 shadow of x
    size_t fixedB = (size_t)(cur - (char*)d_ws);

    const size_t perRowB = 512 + 512 + 384 + 2048;   // v, sbuf, comb, h
    int k = 8;
    while (k > 1 && fixedB + (size_t)k * NPix * perRowB > ws_size) k >>= 1;
    if (fixedB + (size_t)k * NPix * perRowB > ws_size) return;
    const int CM = k * NPix;
    const int nChunks = Bq / k;

    short* v    = (short*)take((size_t)CM * Dm * 2);
    short* sbuf = (short*)take((size_t)CM * Dm * 2);
    float* comb = (float*)take((size_t)CM * 96 * 4);
    short* h    = (short*)take((size_t)CM * FFd * 2);

    // ---- weight repack (bf16, transposed) ----
    repack_kernel<<<dim3(4, 4, Lnum),  256, 0, stream>>>(Wv,   WcatT, Dm,  Dm,  352 * Dm,   0);
    repack_kernel<<<dim3(1, 4, Lnum),  256, 0, stream>>>(Woff, WcatT, Dm,  64,  352 * Dm, 256);
    repack_kernel<<<dim3(1, 4, Lnum),  256, 0, stream>>>(Wa,   WcatT, Dm,  32,  352 * Dm, 320);
    repack_kernel<<<dim3(4, 4, Lnum),  256, 0, stream>>>(Wo,   WoT,   Dm,  Dm,  Dm * Dm,    0);
    repack_kernel<<<dim3(16, 4, Lnum), 256, 0, stream>>>(W1,   W1T,   Dm,  FFd, Dm * FFd,   0);
    repack_kernel<<<dim3(4, 16, Lnum), 256, 0, stream>>>(W2,   W2T,   FFd, Dm,  FFd * Dm,   0);
    bcat_kernel<<<Lnum, 352, 0, stream>>>(bv, boff, ba, bcat);

    // x = src + pos encoding (fp32 + bf16)
    pos_add_kernel<<<Mrows, 256, 0, stream>>>(src, x, xb);

    const int gy   = (CM + 127) / 128;
    const int gLN  = (CM + 63) / 64;

    for (int l = 0; l < Lnum; ++l) {
        const short* WcatT_l = WcatT + (size_t)l * 352 * Dm;
        const short* WoT_l   = WoT   + (size_t)l * Dm * Dm;
        const short* W1T_l   = W1T   + (size_t)l * Dm * FFd;
        const short* W2T_l   = W2T   + (size_t)l * FFd * Dm;

        for (int c = 0; c < nChunks; ++c) {
            size_t rowOff = (size_t)c * CM;
            float* xc  = x  + rowOff * Dm;
            short* xbc = xb + rowOff * Dm;

            // v | comb = xb @ WcatT (split output)
            gemm_mfma_kernel<false, 2><<<dim3(3, gy), 256, 0, stream>>>(
                xbc, WcatT_l, bcat + l * 352, v, comb, CM, Dm, 352, 0);
            // sbuf = deformable sampling (bf16)
            deform_attn_kernel<<<CM / 2, 256, 0, stream>>>(v, comb, sbuf);
            // x = LN(x + sbuf @ WoT + bo); xb = bf16(x)
            gemm_ln_kernel<<<gLN, 256, 0, stream>>>(
                sbuf, WoT_l, bo + l * Dm, g1 + l * Dm, be1 + l * Dm, xc, xbc, CM, Dm);
            // h = gelu(xb @ W1T + b1) (bf16)
            gemm_mfma_kernel<true, 1><<<dim3(8, gy), 256, 0, stream>>>(
                xbc, W1T_l, b1 + l * FFd, h, nullptr, CM, Dm, FFd, FFd);
            // x = LN(x + h @ W2T + b2); xb = bf16(x)
            gemm_ln_kernel<<<gLN, 256, 0, stream>>>(
                h, W2T_l, b2 + l * Dm, g2 + l * Dm, be2 + l * Dm, xc, xbc, CM, FFd);
        }
    }
}